// Round 10
// baseline (422.605 us; speedup 1.0000x reference)
//
#include <hip/hip_runtime.h>
#include <stdint.h>

#define HID    1024
#define INTER  2048
#define NSTATE 16
#define DTRANK 64
#define NHEADS 16
#define NKV    4
#define HDIM   64
#define VHDIM  128
#define ATTN_H 1024
#define K_H    256
#define V_H    512
#define LATENT 3840
#define NCOLS  5888   // LATENT + INTER
#define BATCH  2
#define SEQ    2048
#define T_TOT  4096   // BATCH*SEQ
#define NCHUNK 64
#define CHLEN  32
#define LOG2E  1.44269504f

typedef __bf16 bf16x8 __attribute__((ext_vector_type(8)));
typedef float  f32x4  __attribute__((ext_vector_type(4)));
typedef float  f32x4v __attribute__((ext_vector_type(4)));
typedef unsigned short u16x8 __attribute__((ext_vector_type(8)));

__device__ __forceinline__ float bf2f(unsigned short u) {
    return __uint_as_float(((unsigned int)u) << 16);
}
__device__ __forceinline__ unsigned short f2bf(float f) {
    unsigned int u = __float_as_uint(f);
    u = (u + 0x7fffu + ((u >> 16) & 1u)) >> 16;
    return (unsigned short)u;
}
__device__ __forceinline__ bf16x8 ldb8(const unsigned short* p) {
    return __builtin_bit_cast(bf16x8, *(const u16x8*)p);
}

typedef const __attribute__((address_space(1))) unsigned int* gas_ptr;
typedef __attribute__((address_space(3))) unsigned int* las_ptr;
__device__ __forceinline__ void load_lds16(const void* g, void* l) {
    __builtin_amdgcn_global_load_lds((gas_ptr)g, (las_ptr)l, 16, 0, 0);
}

// ---------------- fused prep: all f32->bf16 converts + W_x pad, one launch ----------------
__global__ void k_prep(const float* __restrict__ x, const float* __restrict__ W_in,
                       const float* __restrict__ W_dt, const float* __restrict__ W_out,
                       const float* __restrict__ W_x,
                       unsigned short* __restrict__ xbf, unsigned short* __restrict__ Winbf,
                       unsigned short* __restrict__ Wdtbf, unsigned short* __restrict__ Woutbf,
                       unsigned short* __restrict__ Wxpad) {
    int i = blockIdx.x * 256 + threadIdx.x;
    const float* src; unsigned short* dst; int off;
    if (i < 524288)        { src = x;     dst = xbf;    off = i; }
    else if (i < 1277952)  { src = W_in;  dst = Winbf;  off = i - 524288; }
    else if (i < 1294336)  { src = W_dt;  dst = Wdtbf;  off = i - 1277952; }
    else if (i < 1556480)  { src = W_out; dst = Woutbf; off = i - 1294336; }
    else {
        int e = (i - 1556480) * 8;
        int row = e >> 11, col = e & 2047;
        u16x8 o;
        if (row < DTRANK + 2 * NSTATE) {
#pragma unroll
            for (int k = 0; k < 8; k++) o[k] = f2bf(W_x[(size_t)row * INTER + col + k]);
        } else {
#pragma unroll
            for (int k = 0; k < 8; k++) o[k] = 0;
        }
        *(u16x8*)(Wxpad + e) = o;
        return;
    }
    f32x4v a = ((const f32x4v*)src)[2 * off];
    f32x4v b = ((const f32x4v*)src)[2 * off + 1];
    u16x8 o;
#pragma unroll
    for (int k = 0; k < 4; k++) { o[k] = f2bf(a[k]); o[k + 4] = f2bf(b[k]); }
    *(u16x8*)(dst + (size_t)off * 8) = o;
}

// ---------------- deep-pipelined GEMM v2: 256x128 tile, BK=64, 3-buffer rotation ----------------
template <int NT>
__launch_bounds__(512)
__global__ void k_gemm8(const unsigned short* __restrict__ A, const unsigned short* __restrict__ B,
                        unsigned short* __restrict__ C, int lda, int ldb, int ldc) {
    __shared__ __align__(16) unsigned short As[3][256 * 64];   // 96 KB
    __shared__ __align__(16) unsigned short Bs[3][128 * 64];   // 48 KB
    const int tid = threadIdx.x;
    const int lane = tid & 63;
    const int w = tid >> 6;                 // 0..7
    const int wm = w >> 1, wn = w & 1;      // 4m x 2n wave grid
    const int l15 = lane & 15, hi = lane >> 4;
    const int nwg = gridDim.x * gridDim.y;
    int lin = blockIdx.y * gridDim.x + blockIdx.x;
    lin = (lin & 7) * (nwg >> 3) + (lin >> 3);       // XCD swizzle (nwg % 8 == 0)
    const int bm = (lin / gridDim.x) * 256;
    const int bn = (lin % gridDim.x) * 128;

    const int srcCol = ((lane & 7) ^ (lane >> 3)) * 8;   // pre-swizzled source col (elements)

    auto stageA = [&](int buf, int kt, int u) {
        int rsb = 64 * u + 8 * w;
        load_lds16(A + (size_t)(bm + rsb + (lane >> 3)) * lda + kt * 64 + srcCol, &As[buf][rsb * 64]);
    };
    auto stageB = [&](int buf, int kt, int u) {
        int rsb = 64 * u + 8 * w;
        load_lds16(B + (size_t)(bn + rsb + (lane >> 3)) * ldb + kt * 64 + srcCol, &Bs[buf][rsb * 64]);
    };

    f32x4 acc[4][4];
#pragma unroll
    for (int i = 0; i < 4; i++)
#pragma unroll
        for (int j = 0; j < 4; j++) acc[i][j] = (f32x4){0.f, 0.f, 0.f, 0.f};

    auto phase = [&](int buf, int kk, auto stageThunk, int vm) {
        bf16x8 a_[4], b_[4];
        const int cc = (kk << 2) + hi;
#pragma unroll
        for (int mi = 0; mi < 4; ++mi) {
            int row = 64 * wm + 16 * mi + l15;
            a_[mi] = ldb8(&As[buf][row * 64 + ((cc ^ (row & 7)) << 3)]);
        }
#pragma unroll
        for (int ni = 0; ni < 4; ++ni) {
            int row = 64 * wn + 16 * ni + l15;
            b_[ni] = ldb8(&Bs[buf][row * 64 + ((cc ^ (row & 7)) << 3)]);
        }
        stageThunk();
        if (vm == 1)      asm volatile("s_waitcnt vmcnt(6)" ::: "memory");
        else if (vm == 2) asm volatile("s_waitcnt vmcnt(0)" ::: "memory");
        __builtin_amdgcn_s_barrier();
        __builtin_amdgcn_s_setprio(1);
#pragma unroll
        for (int mi = 0; mi < 4; ++mi)
#pragma unroll
            for (int ni = 0; ni < 4; ++ni)
                acc[mi][ni] = __builtin_amdgcn_mfma_f32_16x16x32_bf16(a_[mi], b_[ni], acc[mi][ni], 0, 0, 0);
        __builtin_amdgcn_s_setprio(0);
        __builtin_amdgcn_s_barrier();
    };

#pragma unroll
    for (int u = 0; u < 4; ++u) stageA(0, 0, u);
    stageB(0, 0, 0); stageB(0, 0, 1);
#pragma unroll
    for (int u = 0; u < 4; ++u) stageA(1, 1, u);
    stageB(1, 1, 0); stageB(1, 1, 1);
    asm volatile("s_waitcnt vmcnt(6)" ::: "memory");
    __builtin_amdgcn_s_barrier();

    int buf = 0;
    for (int t = 0; t < NT; ++t) {
        const int kt = t + 2;
        const bool st = kt < NT;
        const int pbuf = (buf + 2 >= 3) ? buf - 1 : buf + 2;
        phase(buf, 0, [&] {
            if (st) { stageA(pbuf, kt, 0); stageA(pbuf, kt, 1); stageA(pbuf, kt, 2); }
        }, 0);
        phase(buf, 1, [&] {
            if (st) { stageA(pbuf, kt, 3); stageB(pbuf, kt, 0); stageB(pbuf, kt, 1); }
        }, st ? 1 : 2);
        buf = (buf + 1 >= 3) ? 0 : buf + 1;
    }

#pragma unroll
    for (int mi = 0; mi < 4; ++mi)
#pragma unroll
        for (int ni = 0; ni < 4; ++ni)
#pragma unroll
            for (int r = 0; r < 4; ++r) {
                int grow = bm + 64 * wm + 16 * mi + (hi << 2) + r;
                int gcol = bn + 64 * wn + 16 * ni + l15;
                C[(size_t)grow * ldc + gcol] = f2bf(acc[mi][ni][r]);
            }
}

// ---------------- GEMM: C[M][N] = A[M][K] * B[N][K]^T, bf16 inputs (m97 structure) ----------------
// OUT_MODE 0: bf16; 1: f32; 2: softplus(acc+bias)->bf16; 3: f32 split-K partials (z slices)
template <int OUT_MODE>
__launch_bounds__(256)
__global__ void k_gemm(const unsigned short* __restrict__ A, const unsigned short* __restrict__ B,
                       void* __restrict__ Cout, const float* __restrict__ bias,
                       int M, int N, int K, int lda, int ldb, int ldc) {
    __shared__ __align__(16) unsigned short As[128 * 64];
    __shared__ __align__(16) unsigned short Bs[128 * 64];
    const int tid = threadIdx.x;
    const int lane = tid & 63;
    const int w = tid >> 6;
    const int wm = w >> 1, wn = w & 1;
    const int nwg = gridDim.x * gridDim.y;
    int lin = blockIdx.y * gridDim.x + blockIdx.x;
    lin = (lin & 7) * (nwg >> 3) + (lin >> 3);       // XCD swizzle (nwg % 8 == 0)
    const int bm = (lin / gridDim.x) * 128, bn = (lin % gridDim.x) * 128;
    const size_t koff = (OUT_MODE == 3) ? (size_t)blockIdx.z * K : 0;

    f32x4 acc[4][4];
#pragma unroll
    for (int i = 0; i < 4; i++)
#pragma unroll
        for (int j = 0; j < 4; j++) acc[i][j] = (f32x4){0.f, 0.f, 0.f, 0.f};

    const int nk = K >> 6;
    for (int ks = 0; ks < nk; ++ks) {
        const int k0 = ks << 6;
#pragma unroll
        for (int i = 0; i < 4; ++i) {
            int qb = (w << 6) + (i << 8);      // wave-uniform chunk base
            int q = qb + lane;
            int row = q >> 3, c = q & 7;
            int csrc = c ^ (row & 7);
            load_lds16(A + (size_t)(bm + row) * lda + koff + k0 + csrc * 8, As + qb * 8);
            load_lds16(B + (size_t)(bn + row) * ldb + koff + k0 + csrc * 8, Bs + qb * 8);
        }
        __syncthreads();
#pragma unroll
        for (int kk = 0; kk < 2; ++kk) {
            bf16x8 af[4], bfr[4];
#pragma unroll
            for (int mi = 0; mi < 4; mi++) {
                int row = (wm << 6) + (mi << 4) + (lane & 15);
                int c = (kk << 2) + (lane >> 4);
                af[mi] = ldb8(As + row * 64 + (c ^ (row & 7)) * 8);
            }
#pragma unroll
            for (int ni = 0; ni < 4; ni++) {
                int row = (wn << 6) + (ni << 4) + (lane & 15);
                int c = (kk << 2) + (lane >> 4);
                bfr[ni] = ldb8(Bs + row * 64 + (c ^ (row & 7)) * 8);
            }
#pragma unroll
            for (int mi = 0; mi < 4; mi++)
#pragma unroll
                for (int ni = 0; ni < 4; ni++)
                    acc[mi][ni] = __builtin_amdgcn_mfma_f32_16x16x32_bf16(af[mi], bfr[ni], acc[mi][ni], 0, 0, 0);
        }
        __syncthreads();
    }
#pragma unroll
    for (int mi = 0; mi < 4; mi++)
#pragma unroll
        for (int ni = 0; ni < 4; ni++)
#pragma unroll
            for (int r = 0; r < 4; r++) {
                int grow = bm + (wm << 6) + (mi << 4) + ((lane >> 4) << 2) + r;
                int gcol = bn + (wn << 6) + (ni << 4) + (lane & 15);
                float v = acc[mi][ni][r];
                if (OUT_MODE == 0) {
                    ((unsigned short*)Cout)[(size_t)grow * ldc + gcol] = f2bf(v);
                } else if (OUT_MODE == 1) {
                    ((float*)Cout)[(size_t)grow * ldc + gcol] = v;
                } else if (OUT_MODE == 3) {
                    ((float*)Cout)[(size_t)blockIdx.z * M * ldc + (size_t)grow * ldc + gcol] = v;
                } else {
                    v += bias[gcol];
                    v = (v > 20.f) ? v : log1pf(__expf(v));
                    ((unsigned short*)Cout)[(size_t)grow * ldc + gcol] = f2bf(v);
                }
            }
}

// ---------------- combine 2 split-K partials (deterministic) ----------------
__global__ void k_addout(const float* __restrict__ part, float* __restrict__ out) {
    int i = blockIdx.x * 256 + threadIdx.x;
    f32x4 a = ((const f32x4*)part)[i];
    f32x4 b = ((const f32x4*)(part + (size_t)T_TOT * HID))[i];
    ((f32x4*)out)[i] = a + b;
}

// ---------------- depthwise causal conv (K=4) + SiLU ----------------
__global__ void k_conv(const unsigned short* __restrict__ proj, const float* __restrict__ conv_w,
                       const float* __restrict__ conv_b, unsigned short* __restrict__ xc) {
    int r = blockIdx.x;              // global token row 0..4095
    int d8 = threadIdx.x * 8;
    int t = r & (SEQ - 1);
    float accv[8];
#pragma unroll
    for (int i = 0; i < 8; i++) accv[i] = conv_b[d8 + i];
#pragma unroll
    for (int j = 0; j < 4; j++) {
        int tp = t - 3 + j;
        if (tp < 0) continue;
        u16x8 xv = *(const u16x8*)(proj + (size_t)(r - 3 + j) * NCOLS + (LATENT - INTER) + d8);
#pragma unroll
        for (int i = 0; i < 8; i++) accv[i] += conv_w[(d8 + i) * 4 + j] * bf2f(xv[i]);
    }
    u16x8 o;
#pragma unroll
    for (int i = 0; i < 8; i++) {
        float v = accv[i];
        v = v / (1.f + __expf(-v));
        o[i] = f2bf(v);
    }
    *(u16x8*)(xc + (size_t)r * INTER + d8) = o;
}

// ---------------- rmsnorm of ssm_p split (64 / 16 / 16), sums 8 split-K partials ----------------
__global__ void k_rms3(const float* __restrict__ ssmp, const float* __restrict__ dt_w,
                       const float* __restrict__ B_w, const float* __restrict__ C_w,
                       unsigned short* __restrict__ dtbf, float* __restrict__ Bm, float* __restrict__ Cm) {
    int r = blockIdx.x;
    int tid = threadIdx.x;           // 128 threads
    int lane = tid & 63, w = tid >> 6;
    int c = tid;
    float v = 0.f;
    if (c < 96) {
#pragma unroll
        for (int s = 0; s < 8; s++) v += ssmp[(size_t)s * (T_TOT * 128) + (size_t)r * 128 + c];
    }
    float s = v * v;
    if (w == 0) {
#pragma unroll
        for (int d = 1; d < 64; d <<= 1) s += __shfl_xor(s, d);
        float rms = rsqrtf(s * (1.f / 64.f) + 1e-6f);
        dtbf[(size_t)r * 64 + lane] = f2bf(v * rms * dt_w[lane]);
    } else {
#pragma unroll
        for (int d = 1; d < 16; d <<= 1) s += __shfl_xor(s, d);
        float rms = rsqrtf(s * (1.f / 16.f) + 1e-6f);
        if (lane < 16) Bm[(size_t)r * 16 + lane] = v * rms * B_w[lane];
        else if (lane < 32) Cm[(size_t)r * 16 + (lane - 16)] = v * rms * C_w[lane - 16];
    }
}

// ---------------- chunked selective scan (An pre-scaled by log2(e), exp2f) ----------------
template <int PASS>
__launch_bounds__(256)
__global__ void k_scan_chunk(const unsigned short* __restrict__ deltabf, const unsigned short* __restrict__ xcbf,
                             const float* __restrict__ Bm, const float* __restrict__ Cm,
                             const float* __restrict__ A_log,
                             float* __restrict__ hend, float* __restrict__ sumd,
                             const float* __restrict__ hinit, unsigned short* __restrict__ ybf) {
    __shared__ __align__(16) unsigned short dltS[CHLEN * 256];
    __shared__ __align__(16) unsigned short xvS[CHLEN * 256];
    __shared__ __align__(16) float BsT[CHLEN * 16];
    __shared__ __align__(16) float CsT[CHLEN * 16];
    const int d0 = blockIdx.x * 256;
    const int c = blockIdx.y;
    const int b = blockIdx.z;
    const int tid = threadIdx.x, lane = tid & 63, w = tid >> 6;
    const int t0 = c * CHLEN;
    const size_t rowbase = (size_t)(b * SEQ + t0);

    float An[16];
    {
        const f32x4* ap = (const f32x4*)(A_log + (size_t)(d0 + tid) * 16);
#pragma unroll
        for (int n4 = 0; n4 < 4; n4++) {
            f32x4 av = ap[n4];
#pragma unroll
            for (int j = 0; j < 4; j++) An[n4 * 4 + j] = -LOG2E * __expf(av[j]);
        }
    }

#pragma unroll
    for (int i = 0; i < 4; ++i) {
        int qb = (w << 6) + (i << 8);
        int q = qb + lane;
        int t = q >> 5, coff = q & 31;
        load_lds16(deltabf + (rowbase + t) * INTER + d0 + coff * 8, dltS + qb * 8);
        load_lds16(xcbf + (rowbase + t) * INTER + d0 + coff * 8, xvS + qb * 8);
    }
    if (tid < 128) {
        ((f32x4*)BsT)[tid] = ((const f32x4*)(Bm + rowbase * 16))[tid];
        if (PASS == 2) ((f32x4*)CsT)[tid] = ((const f32x4*)(Cm + rowbase * 16))[tid];
    }
    __syncthreads();

    const size_t sidx = ((size_t)(c * BATCH + b) * INTER + d0 + tid) * 16;
    float h[16];
    if (PASS == 2) {
        const f32x4* hp = (const f32x4*)(hinit + sidx);
#pragma unroll
        for (int n4 = 0; n4 < 4; n4++) {
            f32x4 hv = hp[n4];
#pragma unroll
            for (int j = 0; j < 4; j++) h[n4 * 4 + j] = hv[j];
        }
    } else {
#pragma unroll
        for (int n = 0; n < 16; n++) h[n] = 0.f;
    }
    float sd = 0.f;
    for (int t = 0; t < CHLEN; ++t) {
        float dlt = bf2f(dltS[t * 256 + tid]);
        float xv = bf2f(xvS[t * 256 + tid]);
        float dx = dlt * xv;
        if (PASS == 0) sd += dlt;
        float y = 0.f;
#pragma unroll
        for (int n4 = 0; n4 < 4; ++n4) {
            f32x4 Bt = ((f32x4*)BsT)[t * 4 + n4];
            f32x4 Ct;
            if (PASS == 2) Ct = ((f32x4*)CsT)[t * 4 + n4];
#pragma unroll
            for (int j = 0; j < 4; ++j) {
                int n = n4 * 4 + j;
                float a = exp2f(dlt * An[n]);
                h[n] = h[n] * a + dx * Bt[j];
                if (PASS == 2) y += h[n] * Ct[j];
            }
        }
        if (PASS == 2) ybf[(rowbase + t) * INTER + d0 + tid] = f2bf(y);
    }
    if (PASS == 0) {
        f32x4* hp = (f32x4*)(hend + sidx);
#pragma unroll
        for (int n4 = 0; n4 < 4; n4++) {
            f32x4 hv;
#pragma unroll
            for (int j = 0; j < 4; j++) hv[j] = h[n4 * 4 + j];
            hp[n4] = hv;
        }
        sumd[(size_t)(c * BATCH + b) * INTER + d0 + tid] = sd;
    }
}

// Pass B: propagate h_init across chunks. thread = (b,d,n); 65536 threads.
__global__ void k_scan_prop(const float* __restrict__ A_log, const float* __restrict__ hend,
                            const float* __restrict__ sumd, float* __restrict__ hinit) {
    const int tid = blockIdx.x * 256 + threadIdx.x;   // (b*2048+d)*16+n
    const int n = tid & 15;
    const int d = (tid >> 4) & (INTER - 1);
    const float An = -LOG2E * __expf(A_log[(size_t)d * 16 + n]);
    const int bd = tid >> 4;
    float h = 0.f;
#pragma unroll 1
    for (int cb = 0; cb < NCHUNK / 4; ++cb) {
        float he[4], sdv[4];
#pragma unroll
        for (int j = 0; j < 4; j++) {
            int c = cb * 4 + j;
            he[j] = hend[(size_t)c * 65536 + tid];
            sdv[j] = sumd[(size_t)c * 4096 + bd];
        }
#pragma unroll
        for (int j = 0; j < 4; j++) {
            int c = cb * 4 + j;
            hinit[(size_t)c * 65536 + tid] = h;
            h = he[j] + exp2f(An * sdv[j]) * h;
        }
    }
}

// ---------------- flash attention (causal, GQA 4:1), KV-split x2 ----------------
// R8 COMPUTE structure (Ps LDS, reg prefetch, 2 barriers/tile). Block = (pair, h, b, half):
// processes q-tiles (31-p, p), KV tiles j = half, half+2, ... (even/odd split).
// No-max softmax => partial unnormalized O (bf16) + partial l add exactly; k_fuse normalizes.
__launch_bounds__(256)
__global__ void k_attn(const unsigned short* __restrict__ proj, unsigned short* __restrict__ attnp,
                       float* __restrict__ lsum) {
    __shared__ __align__(16) unsigned short Ks[64 * 64];     // XOR-swz
    __shared__ __align__(16) unsigned short Vt[128 * 64];    // XOR-swz
    __shared__ __align__(16) unsigned short Ps[4 * 16 * 64]; // per-wave, XOR-swz
    const int pair = blockIdx.x;   // 0..15
    const int h = blockIdx.y;
    const int b = blockIdx.z >> 1;
    const int half = blockIdx.z & 1;
    const int g = h >> 2;
    const int tid = threadIdx.x, lane = tid & 63, w = tid >> 6;
    const int l15 = lane & 15, hi = lane >> 4;

    const int krow = tid >> 3, kc = tid & 7;
    const int kp2 = (tid & 31) * 2, vb = tid >> 5;

    const unsigned short* kbase = proj + (size_t)(b * SEQ) * NCOLS + ATTN_H + g * HDIM;
    const unsigned short* vbase = proj + (size_t)(b * SEQ) * NCOLS + (ATTN_H + K_H) + g * VHDIM;

    u16x8 krA[2], vrA[2][2], krB[2], vrB[2][2];

    auto LOAD = [&](u16x8* kr, u16x8 (*vr)[2], int kv) {
        const unsigned short* kp_ = kbase + (size_t)(kv + krow) * NCOLS + kc * 8;
        kr[0] = *(const u16x8*)kp_;
        kr[1] = *(const u16x8*)(kp_ + (size_t)32 * NCOLS);
        const unsigned short* vp_ = vbase + (size_t)(kv + kp2) * NCOLS + vb * 8;
        vr[0][0] = *(const u16x8*)vp_;
        vr[0][1] = *(const u16x8*)(vp_ + NCOLS);
        vr[1][0] = *(const u16x8*)(vp_ + 64);
        vr[1][1] = *(const u16x8*)(vp_ + NCOLS + 64);
    };
    auto WRITE = [&](u16x8* kr, u16x8 (*vr)[2]) {
        int ksw = (kc ^ (krow & 7)) << 3;
        *(u16x8*)&Ks[krow * 64 + ksw] = kr[0];
        *(u16x8*)&Ks[(krow + 32) * 64 + ksw] = kr[1];
#pragma unroll
        for (int hf = 0; hf < 2; hf++) {
            u16x8 va = vr[hf][0], vb2 = vr[hf][1];
#pragma unroll
            for (int i = 0; i < 8; i++) {
                unsigned int pk = (unsigned int)va[i] | ((unsigned int)vb2[i] << 16);
                int r = (vb + hf * 8) * 8 + i;
                *(unsigned int*)&Vt[r * 64 + (((kp2 >> 3) ^ (r & 7)) << 3) + (kp2 & 7)] = pk;
            }
        }
    };

    const float SC = 0.18033688f;   // 0.125 * log2(e)

    for (int phase = 0; phase < 2; ++phase) {
        const int qt = (phase == 0) ? (31 - pair) : pair;   // heavy tile first
        const int qw = qt * 64 + w * 16;
        const int nt2 = (qt >= half) ? (((qt - half) >> 1) + 1) : 0;

        bf16x8 qf[2];
        {
            int qr = qw + l15;
            const unsigned short* qp = proj + (size_t)(b * SEQ + qr) * NCOLS + h * HDIM + hi * 8;
            qf[0] = ldb8(qp);
            qf[1] = ldb8(qp + 32);
        }
        f32x4 O[8];
#pragma unroll
        for (int vf = 0; vf < 8; vf++) O[vf] = (f32x4){0.f, 0.f, 0.f, 0.f};
        float l_[4] = {0.f, 0.f, 0.f, 0.f};

        auto COMPUTE = [&](int kv, bool MASK) {
            const int pbase = w * 1024;   // 16*64 per wave
            f32x4 sv[4];
#pragma unroll
            for (int cf = 0; cf < 4; ++cf) {
                f32x4 s = (f32x4){0.f, 0.f, 0.f, 0.f};
                int row = cf * 16 + l15;
#pragma unroll
                for (int kk = 0; kk < 2; ++kk) {
                    bf16x8 kb = ldb8(&Ks[row * 64 + ((((kk << 2) + hi) ^ (row & 7)) << 3)]);
                    s = __builtin_amdgcn_mfma_f32_16x16x32_bf16(qf[kk], kb, s, 0, 0, 0);
                }
                sv[cf] = s;
            }
            const int qi0 = qw + (hi << 2);
#pragma unroll
            for (int cf = 0; cf < 4; ++cf) {
                int ki = kv + cf * 16 + l15;
#pragma unroll
                for (int rg = 0; rg < 4; ++rg) {
                    float v;
                    if (MASK) v = (ki <= qi0 + rg) ? exp2f(sv[cf][rg] * SC) : 0.f;
                    else      v = exp2f(sv[cf][rg] * SC);
                    l_[rg] += v;
                    int pr = (hi << 2) + rg;
                    int pc = cf * 16 + l15;
                    Ps[pbase + pr * 64 + (((pc >> 3) ^ (pr & 7)) << 3) + (pc & 7)] = f2bf(v);
                }
            }
            bf16x8 pa0 = ldb8(&Ps[pbase + l15 * 64 + ((hi ^ (l15 & 7)) << 3)]);
            bf16x8 pa1 = ldb8(&Ps[pbase + l15 * 64 + (((4 + hi) ^ (l15 & 7)) << 3)]);
#pragma unroll
            for (int vf = 0; vf < 8; ++vf) {
                int vr_ = vf * 16 + l15;
                bf16x8 v0 = ldb8(&Vt[vr_ * 64 + ((hi ^ (vr_ & 7)) << 3)]);
                bf16x8 v1 = ldb8(&Vt[vr_ * 64 + (((4 + hi) ^ (vr_ & 7)) << 3)]);
                O[vf] = __builtin_amdgcn_mfma_f32_16x16x32_bf16(pa0, v0, O[vf], 0, 0, 0);
                O[vf] = __builtin_amdgcn_mfma_f32_16x16x32_bf16(pa1, v1, O[vf], 0, 0, 0);
            }
        };

        if (nt2 > 0) {
            LOAD(krA, vrA, half * 64);
            bool useA = true;
            for (int jj = 0; jj < nt2; ++jj) {
                int j = half + 2 * jj;
                if (useA) {
                    WRITE(krA, vrA);
                    if (jj + 1 < nt2) LOAD(krB, vrB, (j + 2) * 64);
                } else {
                    WRITE(krB, vrB);
                    if (jj + 1 < nt2) LOAD(krA, vrA, (j + 2) * 64);
                }
                __syncthreads();
                COMPUTE(j * 64, j == qt);
                __syncthreads();
                useA = !useA;
            }
        }

#pragma unroll
        for (int dd = 1; dd < 16; dd <<= 1)
#pragma unroll
            for (int rg = 0; rg < 4; ++rg) l_[rg] += __shfl_xor(l_[rg], dd);
        const size_t obase = (size_t)half * T_TOT * INTER;
#pragma unroll
        for (int rg = 0; rg < 4; ++rg) {
            int grow = b * SEQ + qw + (hi << 2) + rg;
            if (l15 == 0) lsum[(size_t)half * T_TOT * 16 + (size_t)grow * 16 + h] = l_[rg];
#pragma unroll
            for (int vf = 0; vf < 8; ++vf) {
                int gcol = h * VHDIM + vf * 16 + l15;
                attnp[obase + (size_t)grow * INTER + gcol] = f2bf(O[vf][rg]);
            }
        }
    }
}

// ---------------- fused epilogue: combine attn halves; y=(scan+xc*D)*silu(gate); rmsnorms ----------------
__launch_bounds__(256)
__global__ void k_fuse(const unsigned short* __restrict__ attnp, const float* __restrict__ lsum,
                       const unsigned short* __restrict__ ybf,
                       const unsigned short* __restrict__ xc, const unsigned short* __restrict__ proj,
                       const float* __restrict__ Dp, const float* __restrict__ ln1,
                       const float* __restrict__ ln2, unsigned short* __restrict__ fused) {
    __shared__ float red[8];
    int r = blockIdx.x, tid = threadIdx.x;
    int c8 = tid * 8;
    int hh = tid >> 4;   // head = c8 / VHDIM
    u16x8 av0 = *(const u16x8*)(attnp + (size_t)r * INTER + c8);
    u16x8 av1 = *(const u16x8*)(attnp + (size_t)T_TOT * INTER + (size_t)r * INTER + c8);
    float linv = 1.f / (lsum[(size_t)r * 16 + hh] + lsum[(size_t)T_TOT * 16 + (size_t)r * 16 + hh]);
    u16x8 yv8 = *(const u16x8*)(ybf + (size_t)r * INTER + c8);
    u16x8 xv8 = *(const u16x8*)(xc + (size_t)r * INTER + c8);
    u16x8 gv8 = *(const u16x8*)(proj + (size_t)r * NCOLS + LATENT + c8);
    float a_[8], y_[8];
    float ssa = 0.f, ssy = 0.f;
#pragma unroll
    for (int i = 0; i < 8; i++) {
        float a = (bf2f(av0[i]) + bf2f(av1[i])) * linv;
        float yv = bf2f(yv8[i]) + bf2f(xv8[i]) * Dp[c8 + i];
        float gg = bf2f(gv8[i]);
        yv *= gg / (1.f + __expf(-gg));
        a_[i] = a; y_[i] = yv;
        ssa += a * a; ssy += yv * yv;
    }
#pragma unroll
    for (int d = 1; d < 64; d <<= 1) { ssa += __shfl_xor(ssa, d); ssy += __shfl_xor(ssy, d); }
    int w = tid >> 6, lane = tid & 63;
    if (lane == 0) { red[w * 2] = ssa; red[w * 2 + 1] = ssy; }
    __syncthreads();
    ssa = red[0] + red[2] + red[4] + red[6];
    ssy = red[1] + red[3] + red[5] + red[7];
    float ra = rsqrtf(ssa * (1.f / 2048.f) + 1e-6f);
    float ry = rsqrtf(ssy * (1.f / 2048.f) + 1e-6f);
    u16x8 o;
#pragma unroll
    for (int i = 0; i < 8; i++) {
        float v = (a_[i] * ra * ln1[c8 + i] + y_[i] * ry * ln2[c8 + i]) * 0.5f;
        o[i] = f2bf(v);
    }
    *(u16x8*)(fused + (size_t)r * INTER + c8) = o;
}

extern "C" void kernel_launch(void* const* d_in, const int* in_sizes, int n_in,
                              void* d_out, int out_size, void* d_ws, size_t ws_size,
                              hipStream_t stream) {
    const float* x      = (const float*)d_in[0];
    const float* W_in   = (const float*)d_in[1];
    const float* conv_w = (const float*)d_in[2];
    const float* conv_b = (const float*)d_in[3];
    const float* W_x    = (const float*)d_in[4];
    const float* dt_w   = (const float*)d_in[5];
    const float* B_w    = (const float*)d_in[6];
    const float* C_w    = (const float*)d_in[7];
    const float* W_dt   = (const float*)d_in[8];
    const float* b_dt   = (const float*)d_in[9];
    const float* A_log  = (const float*)d_in[10];
    const float* Dp     = (const float*)d_in[11];
    const float* ln1    = (const float*)d_in[12];
    const float* ln2    = (const float*)d_in[13];
    const float* W_out  = (const float*)d_in[14];
    float* out = (float*)d_out;

    char* p = (char*)d_ws;
    auto alloc = [&](size_t bytes) -> void* {
        void* r = (void*)p;
        p += (bytes + 255) & ~(size_t)255;
        return r;
    };
    unsigned short* xbf     = (unsigned short*)alloc((size_t)T_TOT * HID * 2);
    unsigned short* Winbf   = (unsigned short*)alloc((size_t)NCOLS * HID * 2);
    unsigned short* projbf  = (unsigned short*)alloc((size_t)T_TOT * NCOLS * 2);
    unsigned short* xcbf    = (unsigned short*)alloc((size_t)T_TOT * INTER * 2);
    unsigned short* Wxpad   = (unsigned short*)alloc((size_t)128 * INTER * 2);
    float*          ssmp    = (float*)alloc((size_t)8 * T_TOT * 128 * 4);
    unsigned short* dtbf    = (unsigned short*)alloc((size_t)T_TOT * DTRANK * 2);
    float*          Bm      = (float*)alloc((size_t)T_TOT * 16 * 4);
    float*          Cm      = (float*)alloc((size_t)T_TOT * 16 * 4);
    unsigned short* Wdtbf   = (unsigned short*)alloc((size_t)INTER * DTRANK * 2);
    unsigned short* deltabf = (unsigned short*)alloc((size_t)T_TOT * INTER * 2);
    unsigned short* ybf     = (unsigned short*)alloc((size_t)T_TOT * INTER * 2);
    unsigned short* attnp   = (unsigned short*)alloc((size_t)2 * T_TOT * INTER * 2);
    float*          lsum    = (float*)alloc((size_t)2 * T_TOT * 16 * 4);
    unsigned short* fusedbf = (unsigned short*)alloc((size_t)T_TOT * INTER * 2);
    unsigned short* Woutbf  = (unsigned short*)alloc((size_t)HID * INTER * 2);
    float*          hendws  = (float*)alloc((size_t)NCHUNK * BATCH * INTER * 16 * 4);
    float*          hinitws = (float*)alloc((size_t)NCHUNK * BATCH * INTER * 16 * 4);
    float*          sumdws  = (float*)alloc((size_t)NCHUNK * BATCH * INTER * 4);
    float*          outpart = (float*)alloc((size_t)2 * T_TOT * HID * 4);

    // fused prep: all converts + pad in one launch (6208 blocks x 256 thr)
    k_prep<<<6208, 256, 0, stream>>>(x, W_in, W_dt, W_out, W_x, xbf, Winbf, Wdtbf, Woutbf, Wxpad);

    // proj = x @ W_in^T -> bf16 [4096][5888]; pipelined GEMM v2, K=1024 -> NT=16
    k_gemm8<16><<<dim3(NCOLS / 128, T_TOT / 256), 512, 0, stream>>>(
        xbf, Winbf, projbf, HID, HID, NCOLS);
    // depthwise conv + silu -> xc bf16
    k_conv<<<T_TOT, 256, 0, stream>>>(projbf, conv_w, conv_b, xcbf);
    // ssm_p = xc @ W_x^T (N padded to 128), split-K=8 partials -> f32
    k_gemm<3><<<dim3(1, T_TOT / 128, 8), 256, 0, stream>>>(
        xcbf, Wxpad, ssmp, nullptr, T_TOT, 128, 256, INTER, INTER, 128);
    k_rms3<<<T_TOT, 128, 0, stream>>>(ssmp, dt_w, B_w, C_w, dtbf, Bm, Cm);
    // delta = softplus(dt @ W_dt^T + b_dt) -> bf16
    k_gemm<2><<<dim3(INTER / 128, T_TOT / 128), 256, 0, stream>>>(
        dtbf, Wdtbf, deltabf, b_dt, T_TOT, INTER, DTRANK, DTRANK, DTRANK, INTER);
    // chunked scan: A (summaries) -> B (propagate) -> C (final + y)
    k_scan_chunk<0><<<dim3(INTER / 256, NCHUNK, BATCH), 256, 0, stream>>>(
        deltabf, xcbf, Bm, Cm, A_log, hendws, sumdws, nullptr, nullptr);
    k_scan_prop<<<256, 256, 0, stream>>>(A_log, hendws, sumdws, hinitws);
    k_scan_chunk<2><<<dim3(INTER / 256, NCHUNK, BATCH), 256, 0, stream>>>(
        deltabf, xcbf, Bm, Cm, A_log, nullptr, nullptr, hinitws, ybf);
    // attention: KV-split x2 (even/odd tiles), 1024 uniform blocks; fuse normalizes
    k_attn<<<dim3(16, NHEADS, BATCH * 2), 256, 0, stream>>>(projbf, attnp, lsum);
    k_fuse<<<T_TOT, 256, 0, stream>>>(attnp, lsum, ybf, xcbf, projbf, Dp, ln1, ln2, fusedbf);
    // out = fused @ W_out^T -> f32, split-K=2 partials + deterministic combine
    k_gemm<3><<<dim3(HID / 128, T_TOT / 128, 2), 256, 0, stream>>>(
        fusedbf, Woutbf, outpart, nullptr, T_TOT, HID, 1024, INTER, INTER, HID);
    k_addout<<<T_TOT * HID / 1024, 256, 0, stream>>>(outpart, out);
}

// Round 11
// 407.395 us; speedup vs baseline: 1.0373x; 1.0373x over previous
//
#include <hip/hip_runtime.h>
#include <stdint.h>

#define HID    1024
#define INTER  2048
#define NSTATE 16
#define DTRANK 64
#define NHEADS 16
#define NKV    4
#define HDIM   64
#define VHDIM  128
#define ATTN_H 1024
#define K_H    256
#define V_H    512
#define LATENT 3840
#define NCOLS  5888   // LATENT + INTER
#define BATCH  2
#define SEQ    2048
#define T_TOT  4096   // BATCH*SEQ
#define NCHUNK 64
#define CHLEN  32
#define LOG2E  1.44269504f

typedef __bf16 bf16x8 __attribute__((ext_vector_type(8)));
typedef float  f32x4  __attribute__((ext_vector_type(4)));
typedef float  f32x4v __attribute__((ext_vector_type(4)));
typedef unsigned short u16x8 __attribute__((ext_vector_type(8)));

__device__ __forceinline__ float bf2f(unsigned short u) {
    return __uint_as_float(((unsigned int)u) << 16);
}
__device__ __forceinline__ unsigned short f2bf(float f) {
    unsigned int u = __float_as_uint(f);
    u = (u + 0x7fffu + ((u >> 16) & 1u)) >> 16;
    return (unsigned short)u;
}
__device__ __forceinline__ bf16x8 ldb8(const unsigned short* p) {
    return __builtin_bit_cast(bf16x8, *(const u16x8*)p);
}

typedef const __attribute__((address_space(1))) unsigned int* gas_ptr;
typedef __attribute__((address_space(3))) unsigned int* las_ptr;
__device__ __forceinline__ void load_lds16(const void* g, void* l) {
    __builtin_amdgcn_global_load_lds((gas_ptr)g, (las_ptr)l, 16, 0, 0);
}

// ---------------- fused prep: all f32->bf16 converts + W_x pad, one launch ----------------
__global__ void k_prep(const float* __restrict__ x, const float* __restrict__ W_in,
                       const float* __restrict__ W_dt, const float* __restrict__ W_out,
                       const float* __restrict__ W_x,
                       unsigned short* __restrict__ xbf, unsigned short* __restrict__ Winbf,
                       unsigned short* __restrict__ Wdtbf, unsigned short* __restrict__ Woutbf,
                       unsigned short* __restrict__ Wxpad) {
    int i = blockIdx.x * 256 + threadIdx.x;
    const float* src; unsigned short* dst; int off;
    if (i < 524288)        { src = x;     dst = xbf;    off = i; }
    else if (i < 1277952)  { src = W_in;  dst = Winbf;  off = i - 524288; }
    else if (i < 1294336)  { src = W_dt;  dst = Wdtbf;  off = i - 1277952; }
    else if (i < 1556480)  { src = W_out; dst = Woutbf; off = i - 1294336; }
    else {
        int e = (i - 1556480) * 8;
        int row = e >> 11, col = e & 2047;
        u16x8 o;
        if (row < DTRANK + 2 * NSTATE) {
#pragma unroll
            for (int k = 0; k < 8; k++) o[k] = f2bf(W_x[(size_t)row * INTER + col + k]);
        } else {
#pragma unroll
            for (int k = 0; k < 8; k++) o[k] = 0;
        }
        *(u16x8*)(Wxpad + e) = o;
        return;
    }
    f32x4v a = ((const f32x4v*)src)[2 * off];
    f32x4v b = ((const f32x4v*)src)[2 * off + 1];
    u16x8 o;
#pragma unroll
    for (int k = 0; k < 4; k++) { o[k] = f2bf(a[k]); o[k + 4] = f2bf(b[k]); }
    *(u16x8*)(dst + (size_t)off * 8) = o;
}

// ---------------- deep-pipelined GEMM v2: 256x128 tile, BK=64, 3-buffer rotation ----------------
template <int NT>
__launch_bounds__(512)
__global__ void k_gemm8(const unsigned short* __restrict__ A, const unsigned short* __restrict__ B,
                        unsigned short* __restrict__ C, int lda, int ldb, int ldc) {
    __shared__ __align__(16) unsigned short As[3][256 * 64];   // 96 KB
    __shared__ __align__(16) unsigned short Bs[3][128 * 64];   // 48 KB
    const int tid = threadIdx.x;
    const int lane = tid & 63;
    const int w = tid >> 6;                 // 0..7
    const int wm = w >> 1, wn = w & 1;      // 4m x 2n wave grid
    const int l15 = lane & 15, hi = lane >> 4;
    const int nwg = gridDim.x * gridDim.y;
    int lin = blockIdx.y * gridDim.x + blockIdx.x;
    lin = (lin & 7) * (nwg >> 3) + (lin >> 3);       // XCD swizzle (nwg % 8 == 0)
    const int bm = (lin / gridDim.x) * 256;
    const int bn = (lin % gridDim.x) * 128;

    const int srcCol = ((lane & 7) ^ (lane >> 3)) * 8;   // pre-swizzled source col (elements)

    auto stageA = [&](int buf, int kt, int u) {
        int rsb = 64 * u + 8 * w;
        load_lds16(A + (size_t)(bm + rsb + (lane >> 3)) * lda + kt * 64 + srcCol, &As[buf][rsb * 64]);
    };
    auto stageB = [&](int buf, int kt, int u) {
        int rsb = 64 * u + 8 * w;
        load_lds16(B + (size_t)(bn + rsb + (lane >> 3)) * ldb + kt * 64 + srcCol, &Bs[buf][rsb * 64]);
    };

    f32x4 acc[4][4];
#pragma unroll
    for (int i = 0; i < 4; i++)
#pragma unroll
        for (int j = 0; j < 4; j++) acc[i][j] = (f32x4){0.f, 0.f, 0.f, 0.f};

    auto phase = [&](int buf, int kk, auto stageThunk, int vm) {
        bf16x8 a_[4], b_[4];
        const int cc = (kk << 2) + hi;
#pragma unroll
        for (int mi = 0; mi < 4; ++mi) {
            int row = 64 * wm + 16 * mi + l15;
            a_[mi] = ldb8(&As[buf][row * 64 + ((cc ^ (row & 7)) << 3)]);
        }
#pragma unroll
        for (int ni = 0; ni < 4; ++ni) {
            int row = 64 * wn + 16 * ni + l15;
            b_[ni] = ldb8(&Bs[buf][row * 64 + ((cc ^ (row & 7)) << 3)]);
        }
        stageThunk();
        if (vm == 1)      asm volatile("s_waitcnt vmcnt(6)" ::: "memory");
        else if (vm == 2) asm volatile("s_waitcnt vmcnt(0)" ::: "memory");
        __builtin_amdgcn_s_barrier();
        __builtin_amdgcn_s_setprio(1);
#pragma unroll
        for (int mi = 0; mi < 4; ++mi)
#pragma unroll
            for (int ni = 0; ni < 4; ++ni)
                acc[mi][ni] = __builtin_amdgcn_mfma_f32_16x16x32_bf16(a_[mi], b_[ni], acc[mi][ni], 0, 0, 0);
        __builtin_amdgcn_s_setprio(0);
        __builtin_amdgcn_s_barrier();
    };

#pragma unroll
    for (int u = 0; u < 4; ++u) stageA(0, 0, u);
    stageB(0, 0, 0); stageB(0, 0, 1);
#pragma unroll
    for (int u = 0; u < 4; ++u) stageA(1, 1, u);
    stageB(1, 1, 0); stageB(1, 1, 1);
    asm volatile("s_waitcnt vmcnt(6)" ::: "memory");
    __builtin_amdgcn_s_barrier();

    int buf = 0;
    for (int t = 0; t < NT; ++t) {
        const int kt = t + 2;
        const bool st = kt < NT;
        const int pbuf = (buf + 2 >= 3) ? buf - 1 : buf + 2;
        phase(buf, 0, [&] {
            if (st) { stageA(pbuf, kt, 0); stageA(pbuf, kt, 1); stageA(pbuf, kt, 2); }
        }, 0);
        phase(buf, 1, [&] {
            if (st) { stageA(pbuf, kt, 3); stageB(pbuf, kt, 0); stageB(pbuf, kt, 1); }
        }, st ? 1 : 2);
        buf = (buf + 1 >= 3) ? 0 : buf + 1;
    }

#pragma unroll
    for (int mi = 0; mi < 4; ++mi)
#pragma unroll
        for (int ni = 0; ni < 4; ++ni)
#pragma unroll
            for (int r = 0; r < 4; ++r) {
                int grow = bm + 64 * wm + 16 * mi + (hi << 2) + r;
                int gcol = bn + 64 * wn + 16 * ni + l15;
                C[(size_t)grow * ldc + gcol] = f2bf(acc[mi][ni][r]);
            }
}

// ---------------- GEMM: C[M][N] = A[M][K] * B[N][K]^T, bf16 inputs (m97 structure) ----------------
// OUT_MODE 0: bf16; 1: f32; 2: softplus(acc+bias)->bf16; 3: f32 split-K partials (z slices)
template <int OUT_MODE>
__launch_bounds__(256)
__global__ void k_gemm(const unsigned short* __restrict__ A, const unsigned short* __restrict__ B,
                       void* __restrict__ Cout, const float* __restrict__ bias,
                       int M, int N, int K, int lda, int ldb, int ldc) {
    __shared__ __align__(16) unsigned short As[128 * 64];
    __shared__ __align__(16) unsigned short Bs[128 * 64];
    const int tid = threadIdx.x;
    const int lane = tid & 63;
    const int w = tid >> 6;
    const int wm = w >> 1, wn = w & 1;
    const int nwg = gridDim.x * gridDim.y;
    int lin = blockIdx.y * gridDim.x + blockIdx.x;
    lin = (lin & 7) * (nwg >> 3) + (lin >> 3);       // XCD swizzle (nwg % 8 == 0)
    const int bm = (lin / gridDim.x) * 128, bn = (lin % gridDim.x) * 128;
    const size_t koff = (OUT_MODE == 3) ? (size_t)blockIdx.z * K : 0;

    f32x4 acc[4][4];
#pragma unroll
    for (int i = 0; i < 4; i++)
#pragma unroll
        for (int j = 0; j < 4; j++) acc[i][j] = (f32x4){0.f, 0.f, 0.f, 0.f};

    const int nk = K >> 6;
    for (int ks = 0; ks < nk; ++ks) {
        const int k0 = ks << 6;
#pragma unroll
        for (int i = 0; i < 4; ++i) {
            int qb = (w << 6) + (i << 8);      // wave-uniform chunk base
            int q = qb + lane;
            int row = q >> 3, c = q & 7;
            int csrc = c ^ (row & 7);
            load_lds16(A + (size_t)(bm + row) * lda + koff + k0 + csrc * 8, As + qb * 8);
            load_lds16(B + (size_t)(bn + row) * ldb + koff + k0 + csrc * 8, Bs + qb * 8);
        }
        __syncthreads();
#pragma unroll
        for (int kk = 0; kk < 2; ++kk) {
            bf16x8 af[4], bfr[4];
#pragma unroll
            for (int mi = 0; mi < 4; mi++) {
                int row = (wm << 6) + (mi << 4) + (lane & 15);
                int c = (kk << 2) + (lane >> 4);
                af[mi] = ldb8(As + row * 64 + (c ^ (row & 7)) * 8);
            }
#pragma unroll
            for (int ni = 0; ni < 4; ni++) {
                int row = (wn << 6) + (ni << 4) + (lane & 15);
                int c = (kk << 2) + (lane >> 4);
                bfr[ni] = ldb8(Bs + row * 64 + (c ^ (row & 7)) * 8);
            }
#pragma unroll
            for (int mi = 0; mi < 4; mi++)
#pragma unroll
                for (int ni = 0; ni < 4; ni++)
                    acc[mi][ni] = __builtin_amdgcn_mfma_f32_16x16x32_bf16(af[mi], bfr[ni], acc[mi][ni], 0, 0, 0);
        }
        __syncthreads();
    }
#pragma unroll
    for (int mi = 0; mi < 4; mi++)
#pragma unroll
        for (int ni = 0; ni < 4; ni++)
#pragma unroll
            for (int r = 0; r < 4; r++) {
                int grow = bm + (wm << 6) + (mi << 4) + ((lane >> 4) << 2) + r;
                int gcol = bn + (wn << 6) + (ni << 4) + (lane & 15);
                float v = acc[mi][ni][r];
                if (OUT_MODE == 0) {
                    ((unsigned short*)Cout)[(size_t)grow * ldc + gcol] = f2bf(v);
                } else if (OUT_MODE == 1) {
                    ((float*)Cout)[(size_t)grow * ldc + gcol] = v;
                } else if (OUT_MODE == 3) {
                    ((float*)Cout)[(size_t)blockIdx.z * M * ldc + (size_t)grow * ldc + gcol] = v;
                } else {
                    v += bias[gcol];
                    v = (v > 20.f) ? v : log1pf(__expf(v));
                    ((unsigned short*)Cout)[(size_t)grow * ldc + gcol] = f2bf(v);
                }
            }
}

// ---------------- combine 2 split-K partials (deterministic) ----------------
__global__ void k_addout(const float* __restrict__ part, float* __restrict__ out) {
    int i = blockIdx.x * 256 + threadIdx.x;
    f32x4 a = ((const f32x4*)part)[i];
    f32x4 b = ((const f32x4*)(part + (size_t)T_TOT * HID))[i];
    ((f32x4*)out)[i] = a + b;
}

// ---------------- depthwise causal conv (K=4) + SiLU ----------------
__global__ void k_conv(const unsigned short* __restrict__ proj, const float* __restrict__ conv_w,
                       const float* __restrict__ conv_b, unsigned short* __restrict__ xc) {
    int r = blockIdx.x;              // global token row 0..4095
    int d8 = threadIdx.x * 8;
    int t = r & (SEQ - 1);
    float accv[8];
#pragma unroll
    for (int i = 0; i < 8; i++) accv[i] = conv_b[d8 + i];
#pragma unroll
    for (int j = 0; j < 4; j++) {
        int tp = t - 3 + j;
        if (tp < 0) continue;
        u16x8 xv = *(const u16x8*)(proj + (size_t)(r - 3 + j) * NCOLS + (LATENT - INTER) + d8);
#pragma unroll
        for (int i = 0; i < 8; i++) accv[i] += conv_w[(d8 + i) * 4 + j] * bf2f(xv[i]);
    }
    u16x8 o;
#pragma unroll
    for (int i = 0; i < 8; i++) {
        float v = accv[i];
        v = v / (1.f + __expf(-v));
        o[i] = f2bf(v);
    }
    *(u16x8*)(xc + (size_t)r * INTER + d8) = o;
}

// ---------------- rmsnorm of ssm_p split (64 / 16 / 16), sums 8 split-K partials ----------------
__global__ void k_rms3(const float* __restrict__ ssmp, const float* __restrict__ dt_w,
                       const float* __restrict__ B_w, const float* __restrict__ C_w,
                       unsigned short* __restrict__ dtbf, float* __restrict__ Bm, float* __restrict__ Cm) {
    int r = blockIdx.x;
    int tid = threadIdx.x;           // 128 threads
    int lane = tid & 63, w = tid >> 6;
    int c = tid;
    float v = 0.f;
    if (c < 96) {
#pragma unroll
        for (int s = 0; s < 8; s++) v += ssmp[(size_t)s * (T_TOT * 128) + (size_t)r * 128 + c];
    }
    float s = v * v;
    if (w == 0) {
#pragma unroll
        for (int d = 1; d < 64; d <<= 1) s += __shfl_xor(s, d);
        float rms = rsqrtf(s * (1.f / 64.f) + 1e-6f);
        dtbf[(size_t)r * 64 + lane] = f2bf(v * rms * dt_w[lane]);
    } else {
#pragma unroll
        for (int d = 1; d < 16; d <<= 1) s += __shfl_xor(s, d);
        float rms = rsqrtf(s * (1.f / 16.f) + 1e-6f);
        if (lane < 16) Bm[(size_t)r * 16 + lane] = v * rms * B_w[lane];
        else if (lane < 32) Cm[(size_t)r * 16 + (lane - 16)] = v * rms * C_w[lane - 16];
    }
}

// ---------------- chunked selective scan (An pre-scaled by log2(e), exp2f) ----------------
template <int PASS>
__launch_bounds__(256)
__global__ void k_scan_chunk(const unsigned short* __restrict__ deltabf, const unsigned short* __restrict__ xcbf,
                             const float* __restrict__ Bm, const float* __restrict__ Cm,
                             const float* __restrict__ A_log,
                             float* __restrict__ hend, float* __restrict__ sumd,
                             const float* __restrict__ hinit, unsigned short* __restrict__ ybf) {
    __shared__ __align__(16) unsigned short dltS[CHLEN * 256];
    __shared__ __align__(16) unsigned short xvS[CHLEN * 256];
    __shared__ __align__(16) float BsT[CHLEN * 16];
    __shared__ __align__(16) float CsT[CHLEN * 16];
    const int d0 = blockIdx.x * 256;
    const int c = blockIdx.y;
    const int b = blockIdx.z;
    const int tid = threadIdx.x, lane = tid & 63, w = tid >> 6;
    const int t0 = c * CHLEN;
    const size_t rowbase = (size_t)(b * SEQ + t0);

    float An[16];
    {
        const f32x4* ap = (const f32x4*)(A_log + (size_t)(d0 + tid) * 16);
#pragma unroll
        for (int n4 = 0; n4 < 4; n4++) {
            f32x4 av = ap[n4];
#pragma unroll
            for (int j = 0; j < 4; j++) An[n4 * 4 + j] = -LOG2E * __expf(av[j]);
        }
    }

#pragma unroll
    for (int i = 0; i < 4; ++i) {
        int qb = (w << 6) + (i << 8);
        int q = qb + lane;
        int t = q >> 5, coff = q & 31;
        load_lds16(deltabf + (rowbase + t) * INTER + d0 + coff * 8, dltS + qb * 8);
        load_lds16(xcbf + (rowbase + t) * INTER + d0 + coff * 8, xvS + qb * 8);
    }
    if (tid < 128) {
        ((f32x4*)BsT)[tid] = ((const f32x4*)(Bm + rowbase * 16))[tid];
        if (PASS == 2) ((f32x4*)CsT)[tid] = ((const f32x4*)(Cm + rowbase * 16))[tid];
    }
    __syncthreads();

    const size_t sidx = ((size_t)(c * BATCH + b) * INTER + d0 + tid) * 16;
    float h[16];
    if (PASS == 2) {
        const f32x4* hp = (const f32x4*)(hinit + sidx);
#pragma unroll
        for (int n4 = 0; n4 < 4; n4++) {
            f32x4 hv = hp[n4];
#pragma unroll
            for (int j = 0; j < 4; j++) h[n4 * 4 + j] = hv[j];
        }
    } else {
#pragma unroll
        for (int n = 0; n < 16; n++) h[n] = 0.f;
    }
    float sd = 0.f;
    for (int t = 0; t < CHLEN; ++t) {
        float dlt = bf2f(dltS[t * 256 + tid]);
        float xv = bf2f(xvS[t * 256 + tid]);
        float dx = dlt * xv;
        if (PASS == 0) sd += dlt;
        float y = 0.f;
#pragma unroll
        for (int n4 = 0; n4 < 4; ++n4) {
            f32x4 Bt = ((f32x4*)BsT)[t * 4 + n4];
            f32x4 Ct;
            if (PASS == 2) Ct = ((f32x4*)CsT)[t * 4 + n4];
#pragma unroll
            for (int j = 0; j < 4; ++j) {
                int n = n4 * 4 + j;
                float a = exp2f(dlt * An[n]);
                h[n] = h[n] * a + dx * Bt[j];
                if (PASS == 2) y += h[n] * Ct[j];
            }
        }
        if (PASS == 2) ybf[(rowbase + t) * INTER + d0 + tid] = f2bf(y);
    }
    if (PASS == 0) {
        f32x4* hp = (f32x4*)(hend + sidx);
#pragma unroll
        for (int n4 = 0; n4 < 4; n4++) {
            f32x4 hv;
#pragma unroll
            for (int j = 0; j < 4; j++) hv[j] = h[n4 * 4 + j];
            hp[n4] = hv;
        }
        sumd[(size_t)(c * BATCH + b) * INTER + d0 + tid] = sd;
    }
}

// Pass B: propagate h_init across chunks. thread = (b,d,n); 65536 threads.
__global__ void k_scan_prop(const float* __restrict__ A_log, const float* __restrict__ hend,
                            const float* __restrict__ sumd, float* __restrict__ hinit) {
    const int tid = blockIdx.x * 256 + threadIdx.x;   // (b*2048+d)*16+n
    const int n = tid & 15;
    const int d = (tid >> 4) & (INTER - 1);
    const float An = -LOG2E * __expf(A_log[(size_t)d * 16 + n]);
    const int bd = tid >> 4;
    float h = 0.f;
#pragma unroll 1
    for (int cb = 0; cb < NCHUNK / 4; ++cb) {
        float he[4], sdv[4];
#pragma unroll
        for (int j = 0; j < 4; j++) {
            int c = cb * 4 + j;
            he[j] = hend[(size_t)c * 65536 + tid];
            sdv[j] = sumd[(size_t)c * 4096 + bd];
        }
#pragma unroll
        for (int j = 0; j < 4; j++) {
            int c = cb * 4 + j;
            hinit[(size_t)c * 65536 + tid] = h;
            h = he[j] + exp2f(An * sdv[j]) * h;
        }
    }
}

// ---------------- flash attention (causal, GQA 4:1) ----------------
// R8 structure + K/V LDS double-buffer -> ONE barrier per KV tile + setprio around MFMA.
// Paired q-tiles (31-p, p) per block -> uniform 33 tiles/block, 512 blocks.
// Race-free: barrier at end of each tile bounds skew to 1 iter; WRITE targets buf[(j+1)&1],
// all current-iter readers use buf[j&1]; Ps is wave-private.
__launch_bounds__(256)
__global__ void k_attn(const unsigned short* __restrict__ proj, unsigned short* __restrict__ attn) {
    __shared__ __align__(16) unsigned short Ks[2][64 * 64];     // 16 KB, XOR-swz
    __shared__ __align__(16) unsigned short Vt[2][128 * 64];    // 32 KB, XOR-swz
    __shared__ __align__(16) unsigned short Ps[4 * 16 * 64];    // 8 KB, per-wave, XOR-swz
    const int pair = blockIdx.x;   // 0..15
    const int h = blockIdx.y;
    const int b = blockIdx.z;
    const int g = h >> 2;
    const int tid = threadIdx.x, lane = tid & 63, w = tid >> 6;
    const int l15 = lane & 15, hi = lane >> 4;

    const int krow = tid >> 3, kc = tid & 7;
    const int kp2 = (tid & 31) * 2, vb = tid >> 5;

    const unsigned short* kbase = proj + (size_t)(b * SEQ) * NCOLS + ATTN_H + g * HDIM;
    const unsigned short* vbase = proj + (size_t)(b * SEQ) * NCOLS + (ATTN_H + K_H) + g * VHDIM;

    u16x8 kr[2], vr[2][2];

    auto LOAD = [&](int kv) {
        const unsigned short* kp_ = kbase + (size_t)(kv + krow) * NCOLS + kc * 8;
        kr[0] = *(const u16x8*)kp_;
        kr[1] = *(const u16x8*)(kp_ + (size_t)32 * NCOLS);
        const unsigned short* vp_ = vbase + (size_t)(kv + kp2) * NCOLS + vb * 8;
        vr[0][0] = *(const u16x8*)vp_;
        vr[0][1] = *(const u16x8*)(vp_ + NCOLS);
        vr[1][0] = *(const u16x8*)(vp_ + 64);
        vr[1][1] = *(const u16x8*)(vp_ + NCOLS + 64);
    };
    auto WRITE = [&](int nb) {
        int ksw = (kc ^ (krow & 7)) << 3;
        *(u16x8*)&Ks[nb][krow * 64 + ksw] = kr[0];
        *(u16x8*)&Ks[nb][(krow + 32) * 64 + ksw] = kr[1];
#pragma unroll
        for (int hf = 0; hf < 2; hf++) {
            u16x8 va = vr[hf][0], vb2 = vr[hf][1];
#pragma unroll
            for (int i = 0; i < 8; i++) {
                unsigned int pk = (unsigned int)va[i] | ((unsigned int)vb2[i] << 16);
                int r = (vb + hf * 8) * 8 + i;
                *(unsigned int*)&Vt[nb][r * 64 + (((kp2 >> 3) ^ (r & 7)) << 3) + (kp2 & 7)] = pk;
            }
        }
    };

    const float SC = 0.18033688f;   // 0.125 * log2(e)

    for (int phase = 0; phase < 2; ++phase) {
        const int qt = (phase == 0) ? (31 - pair) : pair;   // heavy tile first
        const int qw = qt * 64 + w * 16;
        const int ntiles = qt + 1;

        bf16x8 qf[2];
        {
            int qr = qw + l15;
            const unsigned short* qp = proj + (size_t)(b * SEQ + qr) * NCOLS + h * HDIM + hi * 8;
            qf[0] = ldb8(qp);
            qf[1] = ldb8(qp + 32);
        }
        f32x4 O[8];
#pragma unroll
        for (int vf = 0; vf < 8; vf++) O[vf] = (f32x4){0.f, 0.f, 0.f, 0.f};
        float l_[4] = {0.f, 0.f, 0.f, 0.f};

        auto COMPUTE = [&](int kv, bool MASK, int cb) {
            const int pbase = w * 1024;   // 16*64 per wave
            f32x4 sv[4];
            __builtin_amdgcn_s_setprio(1);
#pragma unroll
            for (int cf = 0; cf < 4; ++cf) {
                f32x4 s = (f32x4){0.f, 0.f, 0.f, 0.f};
                int row = cf * 16 + l15;
#pragma unroll
                for (int kk = 0; kk < 2; ++kk) {
                    bf16x8 kb = ldb8(&Ks[cb][row * 64 + ((((kk << 2) + hi) ^ (row & 7)) << 3)]);
                    s = __builtin_amdgcn_mfma_f32_16x16x32_bf16(qf[kk], kb, s, 0, 0, 0);
                }
                sv[cf] = s;
            }
            __builtin_amdgcn_s_setprio(0);
            const int qi0 = qw + (hi << 2);
#pragma unroll
            for (int cf = 0; cf < 4; ++cf) {
                int ki = kv + cf * 16 + l15;
#pragma unroll
                for (int rg = 0; rg < 4; ++rg) {
                    float v;
                    if (MASK) v = (ki <= qi0 + rg) ? exp2f(sv[cf][rg] * SC) : 0.f;
                    else      v = exp2f(sv[cf][rg] * SC);
                    l_[rg] += v;
                    int pr = (hi << 2) + rg;
                    int pc = cf * 16 + l15;
                    Ps[pbase + pr * 64 + (((pc >> 3) ^ (pr & 7)) << 3) + (pc & 7)] = f2bf(v);
                }
            }
            bf16x8 pa0 = ldb8(&Ps[pbase + l15 * 64 + ((hi ^ (l15 & 7)) << 3)]);
            bf16x8 pa1 = ldb8(&Ps[pbase + l15 * 64 + (((4 + hi) ^ (l15 & 7)) << 3)]);
            __builtin_amdgcn_s_setprio(1);
#pragma unroll
            for (int vf = 0; vf < 8; ++vf) {
                int vr_ = vf * 16 + l15;
                bf16x8 v0 = ldb8(&Vt[cb][vr_ * 64 + ((hi ^ (vr_ & 7)) << 3)]);
                bf16x8 v1 = ldb8(&Vt[cb][vr_ * 64 + (((4 + hi) ^ (vr_ & 7)) << 3)]);
                O[vf] = __builtin_amdgcn_mfma_f32_16x16x32_bf16(pa0, v0, O[vf], 0, 0, 0);
                O[vf] = __builtin_amdgcn_mfma_f32_16x16x32_bf16(pa1, v1, O[vf], 0, 0, 0);
            }
            __builtin_amdgcn_s_setprio(0);
        };

        LOAD(0);
        WRITE(0);
        __syncthreads();
        for (int j = 0; j < ntiles; ++j) {
            if (j + 1 < ntiles) LOAD((j + 1) * 64);       // issue early, hides under COMPUTE
            COMPUTE(j * 64, j == ntiles - 1, j & 1);
            if (j + 1 < ntiles) WRITE((j + 1) & 1);       // write to the buffer nobody reads this iter
            __syncthreads();                               // single barrier per KV tile
        }

#pragma unroll
        for (int dd = 1; dd < 16; dd <<= 1)
#pragma unroll
            for (int rg = 0; rg < 4; ++rg) l_[rg] += __shfl_xor(l_[rg], dd);
#pragma unroll
        for (int rg = 0; rg < 4; ++rg) {
            float inv = 1.f / l_[rg];
            int grow = b * SEQ + qw + (hi << 2) + rg;
#pragma unroll
            for (int vf = 0; vf < 8; ++vf) {
                int gcol = h * VHDIM + vf * 16 + l15;
                attn[(size_t)grow * INTER + gcol] = f2bf(O[vf][rg] * inv);
            }
        }
    }
}

// ---------------- fused epilogue: y=(scan+xc*D)*silu(gate); rmsnorms; mix ----------------
__launch_bounds__(256)
__global__ void k_fuse(const unsigned short* __restrict__ attn, const unsigned short* __restrict__ ybf,
                       const unsigned short* __restrict__ xc, const unsigned short* __restrict__ proj,
                       const float* __restrict__ Dp, const float* __restrict__ ln1,
                       const float* __restrict__ ln2, unsigned short* __restrict__ fused) {
    __shared__ float red[8];
    int r = blockIdx.x, tid = threadIdx.x;
    int c8 = tid * 8;
    u16x8 av = *(const u16x8*)(attn + (size_t)r * INTER + c8);
    u16x8 yv8 = *(const u16x8*)(ybf + (size_t)r * INTER + c8);
    u16x8 xv8 = *(const u16x8*)(xc + (size_t)r * INTER + c8);
    u16x8 gv8 = *(const u16x8*)(proj + (size_t)r * NCOLS + LATENT + c8);
    float a_[8], y_[8];
    float ssa = 0.f, ssy = 0.f;
#pragma unroll
    for (int i = 0; i < 8; i++) {
        float a = bf2f(av[i]);
        float yv = bf2f(yv8[i]) + bf2f(xv8[i]) * Dp[c8 + i];
        float gg = bf2f(gv8[i]);
        yv *= gg / (1.f + __expf(-gg));
        a_[i] = a; y_[i] = yv;
        ssa += a * a; ssy += yv * yv;
    }
#pragma unroll
    for (int d = 1; d < 64; d <<= 1) { ssa += __shfl_xor(ssa, d); ssy += __shfl_xor(ssy, d); }
    int w = tid >> 6, lane = tid & 63;
    if (lane == 0) { red[w * 2] = ssa; red[w * 2 + 1] = ssy; }
    __syncthreads();
    ssa = red[0] + red[2] + red[4] + red[6];
    ssy = red[1] + red[3] + red[5] + red[7];
    float ra = rsqrtf(ssa * (1.f / 2048.f) + 1e-6f);
    float ry = rsqrtf(ssy * (1.f / 2048.f) + 1e-6f);
    u16x8 o;
#pragma unroll
    for (int i = 0; i < 8; i++) {
        float v = (a_[i] * ra * ln1[c8 + i] + y_[i] * ry * ln2[c8 + i]) * 0.5f;
        o[i] = f2bf(v);
    }
    *(u16x8*)(fused + (size_t)r * INTER + c8) = o;
}

extern "C" void kernel_launch(void* const* d_in, const int* in_sizes, int n_in,
                              void* d_out, int out_size, void* d_ws, size_t ws_size,
                              hipStream_t stream) {
    const float* x      = (const float*)d_in[0];
    const float* W_in   = (const float*)d_in[1];
    const float* conv_w = (const float*)d_in[2];
    const float* conv_b = (const float*)d_in[3];
    const float* W_x    = (const float*)d_in[4];
    const float* dt_w   = (const float*)d_in[5];
    const float* B_w    = (const float*)d_in[6];
    const float* C_w    = (const float*)d_in[7];
    const float* W_dt   = (const float*)d_in[8];
    const float* b_dt   = (const float*)d_in[9];
    const float* A_log  = (const float*)d_in[10];
    const float* Dp     = (const float*)d_in[11];
    const float* ln1    = (const float*)d_in[12];
    const float* ln2    = (const float*)d_in[13];
    const float* W_out  = (const float*)d_in[14];
    float* out = (float*)d_out;

    char* p = (char*)d_ws;
    auto alloc = [&](size_t bytes) -> void* {
        void* r = (void*)p;
        p += (bytes + 255) & ~(size_t)255;
        return r;
    };
    unsigned short* xbf     = (unsigned short*)alloc((size_t)T_TOT * HID * 2);
    unsigned short* Winbf   = (unsigned short*)alloc((size_t)NCOLS * HID * 2);
    unsigned short* projbf  = (unsigned short*)alloc((size_t)T_TOT * NCOLS * 2);
    unsigned short* xcbf    = (unsigned short*)alloc((size_t)T_TOT * INTER * 2);
    unsigned short* Wxpad   = (unsigned short*)alloc((size_t)128 * INTER * 2);
    float*          ssmp    = (float*)alloc((size_t)8 * T_TOT * 128 * 4);
    unsigned short* dtbf    = (unsigned short*)alloc((size_t)T_TOT * DTRANK * 2);
    float*          Bm      = (float*)alloc((size_t)T_TOT * 16 * 4);
    float*          Cm      = (float*)alloc((size_t)T_TOT * 16 * 4);
    unsigned short* Wdtbf   = (unsigned short*)alloc((size_t)INTER * DTRANK * 2);
    unsigned short* deltabf = (unsigned short*)alloc((size_t)T_TOT * INTER * 2);
    unsigned short* ybf     = (unsigned short*)alloc((size_t)T_TOT * INTER * 2);
    unsigned short* attnbf  = (unsigned short*)alloc((size_t)T_TOT * INTER * 2);
    unsigned short* fusedbf = (unsigned short*)alloc((size_t)T_TOT * INTER * 2);
    unsigned short* Woutbf  = (unsigned short*)alloc((size_t)HID * INTER * 2);
    float*          hendws  = (float*)alloc((size_t)NCHUNK * BATCH * INTER * 16 * 4);
    float*          hinitws = (float*)alloc((size_t)NCHUNK * BATCH * INTER * 16 * 4);
    float*          sumdws  = (float*)alloc((size_t)NCHUNK * BATCH * INTER * 4);
    float*          outpart = (float*)alloc((size_t)2 * T_TOT * HID * 4);

    // fused prep: all converts + pad in one launch (6208 blocks x 256 thr)
    k_prep<<<6208, 256, 0, stream>>>(x, W_in, W_dt, W_out, W_x, xbf, Winbf, Wdtbf, Woutbf, Wxpad);

    // proj = x @ W_in^T -> bf16 [4096][5888]; pipelined GEMM v2, K=1024 -> NT=16
    k_gemm8<16><<<dim3(NCOLS / 128, T_TOT / 256), 512, 0, stream>>>(
        xbf, Winbf, projbf, HID, HID, NCOLS);
    // depthwise conv + silu -> xc bf16
    k_conv<<<T_TOT, 256, 0, stream>>>(projbf, conv_w, conv_b, xcbf);
    // ssm_p = xc @ W_x^T (N padded to 128), split-K=8 partials -> f32
    k_gemm<3><<<dim3(1, T_TOT / 128, 8), 256, 0, stream>>>(
        xcbf, Wxpad, ssmp, nullptr, T_TOT, 128, 256, INTER, INTER, 128);
    k_rms3<<<T_TOT, 128, 0, stream>>>(ssmp, dt_w, B_w, C_w, dtbf, Bm, Cm);
    // delta = softplus(dt @ W_dt^T + b_dt) -> bf16
    k_gemm<2><<<dim3(INTER / 128, T_TOT / 128), 256, 0, stream>>>(
        dtbf, Wdtbf, deltabf, b_dt, T_TOT, INTER, DTRANK, DTRANK, DTRANK, INTER);
    // chunked scan: A (summaries) -> B (propagate) -> C (final + y)
    k_scan_chunk<0><<<dim3(INTER / 256, NCHUNK, BATCH), 256, 0, stream>>>(
        deltabf, xcbf, Bm, Cm, A_log, hendws, sumdws, nullptr, nullptr);
    k_scan_prop<<<256, 256, 0, stream>>>(A_log, hendws, sumdws, hinitws);
    k_scan_chunk<2><<<dim3(INTER / 256, NCHUNK, BATCH), 256, 0, stream>>>(
        deltabf, xcbf, Bm, Cm, A_log, nullptr, nullptr, hinitws, ybf);
    // attention: 512 uniform paired blocks, dbuf KV, 1 barrier/tile
    k_attn<<<dim3(16, NHEADS, BATCH), 256, 0, stream>>>(projbf, attnbf);
    k_fuse<<<T_TOT, 256, 0, stream>>>(attnbf, ybf, xcbf, projbf, Dp, ln1, ln2, fusedbf);
    // out = fused @ W_out^T -> f32, split-K=2 partials + deterministic combine
    k_gemm<3><<<dim3(HID / 128, T_TOT / 128, 2), 256, 0, stream>>>(
        fusedbf, Woutbf, outpart, nullptr, T_TOT, HID, 1024, INTER, INTER, HID);
    k_addout<<<T_TOT * HID / 1024, 256, 0, stream>>>(outpart, out);
}